// Round 16
// baseline (57.533 us; speedup 1.0000x reference)
//
#include <hip/hip_runtime.h>
#include <hip/hip_fp16.h>

// ButterflyRotation: 12 butterfly layers over rows of 4096 fp32.
// R16: wave-internal butterfly. e = 8t+k ownership throughout layers 0-8:
//   layers 0-2 in-thread; layers 3-7 cross-lane via ds_swizzle (XOR 1..16);
//   layer 8 via ds_bpermute (lane^32). Single LDS transpose + ONE barrier,
//   then layers 9-11 in-thread on e = t+512m; NT coalesced store.
// Pair-shared angle groups read at (t & ~bit) -> partners share cache line
// (per-block angle traffic = R10's 96 KB). f16 {1-cos,sin} packed table.
// BLOCK=512, 2 rows packed v2f, 32 KiB LDS, grid 4096 dispatch-ordered.

#define DIM    4096
#define LAYERS 12
#define BATCH  8192
#define NANG   2048
#define BLOCK  512

typedef unsigned int u32;
typedef float v2f __attribute__((ext_vector_type(2)));

#define BAR() do {                                             \
    asm volatile("s_waitcnt lgkmcnt(0)" ::: "memory");         \
    __builtin_amdgcn_sched_barrier(0);                         \
    __builtin_amdgcn_s_barrier();                              \
} while (0)

__device__ __forceinline__ int swzQ(int Q) {
    return Q ^ ((Q >> 3) & 7) ^ ((Q >> 6) & 7);
}
__device__ __forceinline__ int uslot(int e) {
    return 2 * swzQ(e >> 1) + (e & 1);
}
__device__ __forceinline__ constexpr int inner_idx(int m, int jj) {
    return ((m >> (jj + 1)) << jj) + (m & ((1 << jj) - 1));
}

__device__ __forceinline__ void rot2(v2f& xl, v2f& xr, float c, float s) {
    v2f nl = c * xl + s * xr;
    v2f nr = c * xr - s * xl;
    xl = nl; xr = nr;
}

// ---- table build ----------------------------------------------------------
// u32 = {h(1-c) | h(s)<<16}. 18 groups x 512 threads x uint4 (147 KiB):
//  groups 0-2:   layers 0-2, thread-keyed (R10 region-0 mapping)
//  groups 3-14:  layers 3-8 (2 groups/layer), PAIR-keyed at left thread tL;
//                readers use addr (t & ~2^(l-3)) so partners share the slot
//  groups 15-17: layers 9-11, thread-keyed (R10 region-3 mapping)
__global__ void __launch_bounds__(256) cs_kernel(const float* __restrict__ angles,
                                                 u32* __restrict__ TH, int n) {
    int i = blockIdx.x * blockDim.x + threadIdx.x;
    if (i >= n) return;
    float a = angles[i];
    float c = cosf(a), s = sinf(a);
    u32 lo = (u32)__half_as_ushort(__float2half(1.0f - c));
    u32 hi = (u32)__half_as_ushort(__float2half(s));
    u32 packed = lo | (hi << 16);
    int l = i >> 11, aa = i & 2047;
    if (l < 3) {
        int t = aa >> 2, ii = aa & 3;
        TH[((l * 512) + t) * 4 + ii] = packed;
    } else if (l < 9) {
        int hi_ = aa >> l, lo_ = aa & ((1 << l) - 1);
        int e_left = (hi_ << (l + 1)) + lo_;      // left element of the pair
        int k = e_left & 7;
        int tL = e_left >> 3;                     // bit (l-3) of tL is clear
        int group = 3 + (l - 3) * 2 + (k >> 2);
        TH[((group * 512) + tL) * 4 + (k & 3)] = packed;
    } else {
        int ii = aa >> 9, t = aa & 511;
        int group = 15 + (l - 9);
        TH[((group * 512) + t) * 4 + ii] = packed;
    }
}

// ---- helpers --------------------------------------------------------------
#define UNPACK12(Ua, Ub, Uc, ca, sa) do {                                  \
    const u32 _u[12] = {Ua.x, Ua.y, Ua.z, Ua.w, Ub.x, Ub.y, Ub.z, Ub.w,    \
                        Uc.x, Uc.y, Uc.z, Uc.w};                           \
    _Pragma("unroll")                                                      \
    for (int a = 0; a < 12; ++a) {                                         \
        __half2 h2 = *reinterpret_cast<const __half2*>(&_u[a]);            \
        float2 f = __half22float2(h2);                                     \
        ca[a] = 1.0f - f.x;                                                \
        sa[a] = f.y;                                                       \
    }                                                                      \
} while (0)

#define PHASE_ROTS(ca, sa, w)                                              \
    _Pragma("unroll")                                                      \
    for (int jj = 0; jj < 3; ++jj) {                                       \
        const int st = 1 << jj;                                            \
        _Pragma("unroll")                                                  \
        for (int m = 0; m < 8; ++m) {                                      \
            if (!(m & st)) {                                               \
                const int a = jj * 4 + inner_idx(m, jj);                   \
                rot2(w[m], w[m + st], ca[a], sa[a]);                       \
            }                                                              \
        }                                                                  \
    }

template<int IMM>
__device__ __forceinline__ v2f swz2(v2f v) {
    int x = __builtin_amdgcn_ds_swizzle(__float_as_int(v.x), IMM);
    int y = __builtin_amdgcn_ds_swizzle(__float_as_int(v.y), IMM);
    return v2f{__int_as_float(x), __int_as_float(y)};
}
__device__ __forceinline__ v2f bperm2(v2f v, int bidx) {
    int x = __builtin_amdgcn_ds_bpermute(bidx, __float_as_int(v.x));
    int y = __builtin_amdgcn_ds_bpermute(bidx, __float_as_int(v.y));
    return v2f{__int_as_float(x), __int_as_float(y)};
}

// one cross-lane layer: new = c*own + (sign-folded s)*other
// LBIT = lane bit of the pair (1,2,4,8,16); IMM = ds_swizzle XOR pattern
template<int LBIT, int IMM>
__device__ __forceinline__ void shfl_layer(v2f* w, const uint4& Ua,
                                           const uint4& Ub, int lane) {
    float cc[8], ss[8];
    {
        const u32 _u[8] = {Ua.x, Ua.y, Ua.z, Ua.w, Ub.x, Ub.y, Ub.z, Ub.w};
        #pragma unroll
        for (int a = 0; a < 8; ++a) {
            __half2 h2 = *reinterpret_cast<const __half2*>(&_u[a]);
            float2 f = __half22float2(h2);
            cc[a] = 1.0f - f.x;
            ss[a] = f.y;
        }
    }
    const u32 smask = (lane & LBIT) ? 0x80000000u : 0u;
    #pragma unroll
    for (int m = 0; m < 8; ++m) {
        v2f other = swz2<IMM>(w[m]);
        float se = __int_as_float(__float_as_int(ss[m]) ^ smask);
        w[m] = cc[m] * w[m] + se * other;
    }
}

__global__ void __launch_bounds__(BLOCK, 6)
butterfly_kernel(const float* __restrict__ x, const uint4* __restrict__ TH4,
                 float* __restrict__ out) {
    __shared__ v2f buf[DIM];                // 32 KiB interleaved {r0[e], r1[e]}
    const int t = threadIdx.x;
    const int lane = t & 63;
    const long row0 = (long)blockIdx.x * 2;

    v2f w[8];
    float ca[12], sa[12];

    // ---- prologue loads: x, layers 0-2 angles, layer-3 angles ----
    uint4 A0 = TH4[0 * 512 + t], A1 = TH4[1 * 512 + t], A2 = TH4[2 * 512 + t];
    {
        const float* p0 = x + row0 * DIM + 8 * t;
        const float* p1 = p0 + DIM;
        float4 a = *(const float4*)(p0),  b = *(const float4*)(p0 + 4);
        float4 c = *(const float4*)(p1),  d = *(const float4*)(p1 + 4);
        w[0] = v2f{a.x, c.x}; w[1] = v2f{a.y, c.y};
        w[2] = v2f{a.z, c.z}; w[3] = v2f{a.w, c.w};
        w[4] = v2f{b.x, d.x}; w[5] = v2f{b.y, d.y};
        w[6] = v2f{b.z, d.z}; w[7] = v2f{b.w, d.w};
    }
    uint4 B0 = TH4[3 * 512 + (t & ~1)],  B1 = TH4[4 * 512 + (t & ~1)];

    // ===== layers 0-2 (in-thread, strides 1,2,4) =====
    UNPACK12(A0, A1, A2, ca, sa);
    PHASE_ROTS(ca, sa, w)

    // ===== layers 3-7: ds_swizzle XOR 1,2,4,8,16 =====
    uint4 C0 = TH4[5 * 512 + (t & ~2)],  C1 = TH4[6 * 512 + (t & ~2)];
    shfl_layer<1, 0x041F>(w, B0, B1, lane);
    B0 = TH4[7 * 512 + (t & ~4)];  B1 = TH4[8 * 512 + (t & ~4)];
    shfl_layer<2, 0x081F>(w, C0, C1, lane);
    C0 = TH4[9 * 512 + (t & ~8)];  C1 = TH4[10 * 512 + (t & ~8)];
    shfl_layer<4, 0x101F>(w, B0, B1, lane);
    B0 = TH4[11 * 512 + (t & ~16)]; B1 = TH4[12 * 512 + (t & ~16)];
    shfl_layer<8, 0x201F>(w, C0, C1, lane);
    C0 = TH4[13 * 512 + (t & ~32)]; C1 = TH4[14 * 512 + (t & ~32)];
    shfl_layer<16, 0x401F>(w, B0, B1, lane);

    // prefetch layers 9-11 angles (fly across the barrier)
    uint4 D0 = TH4[15 * 512 + t], D1 = TH4[16 * 512 + t], D2 = TH4[17 * 512 + t];

    // ===== layer 8: ds_bpermute lane^32 =====
    {
        float cc[8], ss[8];
        const u32 _u[8] = {C0.x, C0.y, C0.z, C0.w, C1.x, C1.y, C1.z, C1.w};
        #pragma unroll
        for (int a = 0; a < 8; ++a) {
            __half2 h2 = *reinterpret_cast<const __half2*>(&_u[a]);
            float2 f = __half22float2(h2);
            cc[a] = 1.0f - f.x;
            ss[a] = f.y;
        }
        const u32 smask = (lane & 32) ? 0x80000000u : 0u;
        const int bidx = (lane ^ 32) << 2;
        #pragma unroll
        for (int m = 0; m < 8; ++m) {
            v2f other = bperm2(w[m], bidx);
            float se = __int_as_float(__float_as_int(ss[m]) ^ smask);
            w[m] = cc[m] * w[m] + se * other;
        }
    }

    // ===== transpose: e=8t+k -> e=t+512m (ONE barrier) =====
    #pragma unroll
    for (int q = 0; q < 4; ++q) {
        *(float4*)(&buf[2 * swzQ(4 * t + q)]) =
            make_float4(w[2*q].x, w[2*q].y, w[2*q+1].x, w[2*q+1].y);
    }
    BAR();
    #pragma unroll
    for (int m = 0; m < 8; ++m) w[m] = buf[uslot(t + 512 * m)];

    // ===== layers 9-11 (in-thread on m, strides 1,2,4) =====
    UNPACK12(D0, D1, D2, ca, sa);
    PHASE_ROTS(ca, sa, w)

    // ===== NT coalesced store =====
    {
        float* o0 = out + row0 * DIM + t;
        float* o1 = o0 + DIM;
        #pragma unroll
        for (int m = 0; m < 8; ++m) {
            __builtin_nontemporal_store(w[m].x, o0 + (m << 9));
            __builtin_nontemporal_store(w[m].y, o1 + (m << 9));
        }
    }
}

extern "C" void kernel_launch(void* const* d_in, const int* in_sizes, int n_in,
                              void* d_out, int out_size, void* d_ws, size_t ws_size,
                              hipStream_t stream) {
    (void)in_sizes; (void)n_in; (void)out_size; (void)ws_size;
    const float* x      = (const float*)d_in[0];
    const float* angles = (const float*)d_in[1];
    float* out = (float*)d_out;

    const int n = LAYERS * NANG;                    // 147 KiB table
    cs_kernel<<<(n + 255) / 256, 256, 0, stream>>>(angles, (u32*)d_ws, n);
    butterfly_kernel<<<BATCH / 2, BLOCK, 0, stream>>>(x, (const uint4*)d_ws, out);
}

// Round 17
// 52.937 us; speedup vs baseline: 1.0868x; 1.0868x over previous
//
#include <hip/hip_runtime.h>
#include <hip/hip_fp16.h>

// ButterflyRotation: 12 butterfly layers over rows of 4096 fp32.
// R17 = R10 (best: 53.15 us) with x-loads issued before angle loads.
// Structure: BLOCK=512, 2 rows packed v2f in interleaved 32 KiB LDS,
// radix-8 x 4 phases, f16 {1-cos,sin} transposed table (96 KiB),
// one-phase-ahead angle prefetch, 3 lgkm-only barriers, grid 4096
// dispatch-ordered (grid-level restructures destroy L3 locality: R6/R12).
//   P1: e = 8t+m                    -> layers 0-2   (x direct from global)
//   P2: e = 64(t>>3)+8m+(t&7)       -> layers 3-5
//   P3: e = 512(t>>6)+64m+(t&63)    -> layers 6-8
//   P4: e = t+512m                  -> layers 9-11  (coalesced store)

#define DIM    4096
#define LAYERS 12
#define BATCH  8192
#define NANG   2048
#define BLOCK  512

typedef unsigned int u32;
typedef float v2f __attribute__((ext_vector_type(2)));

// lgkm-only barrier: global loads stay in flight across it
#define BAR() do {                                             \
    asm volatile("s_waitcnt lgkmcnt(0)" ::: "memory");         \
    __builtin_amdgcn_sched_barrier(0);                         \
    __builtin_amdgcn_s_barrier();                              \
} while (0)

// quad-level swizzle (involution: only bits 0-2 change)
__device__ __forceinline__ int swzQ(int Q) {
    return Q ^ ((Q >> 3) & 7) ^ ((Q >> 6) & 7);
}
// element -> interleaved 8B-unit slot (quad swizzle in packed space)
__device__ __forceinline__ int uslot(int e) {
    return 2 * swzQ(e >> 1) + (e & 1);
}
// butterfly sub-index for left element m at local level jj (stride 2^jj)
__device__ __forceinline__ constexpr int inner_idx(int m, int jj) {
    return ((m >> (jj + 1)) << jj) + (m & ((1 << jj) - 1));
}

// packed rotation on both rows at once
__device__ __forceinline__ void rot2(v2f& xl, v2f& xr, float c, float s) {
    v2f nl = c * xl + s * xr;
    v2f nr = c * xr - s * xl;
    xl = nl; xr = nr;
}

// f16-packed transposed table: 12 groups x 512 threads x uint4
// (u32 component a&3 of group (region*3 + (a>>2)) holds angle a = jj*4+ii
//  of that phase for thread t, packed {h(1-c) | h(s)<<16}). 96 KiB.
__global__ void __launch_bounds__(256) cs_kernel(const float* __restrict__ angles,
                                                 u32* __restrict__ TH, int n) {
    int i = blockIdx.x * blockDim.x + threadIdx.x;
    if (i >= n) return;
    float a = angles[i];
    float c = cosf(a), s = sinf(a);
    int l = i >> 11, aa = i & 2047;
    int region, jj, t, ii;
    if (l < 3)      { region = 0; jj = l;     t = aa >> 2;  ii = aa & 3; }
    else if (l < 6) { region = 1; jj = l - 3; int B = aa >> 5, r = aa & 31;
                      ii = r >> 3; t = 8 * B + (r & 7); }
    else if (l < 9) { region = 2; jj = l - 6; int S = aa >> 8, r = aa & 255;
                      ii = r >> 6; t = 64 * S + (r & 63); }
    else            { region = 3; jj = l - 9; ii = aa >> 9; t = aa & 511; }
    int a_idx = jj * 4 + ii;
    int flat = ((region * 3 + (a_idx >> 2)) * 512 + t) * 4 + (a_idx & 3);
    u32 lo = (u32)__half_as_ushort(__float2half(1.0f - c));
    u32 hi = (u32)__half_as_ushort(__float2half(s));
    TH[flat] = lo | (hi << 16);
}

// unpack 3 uint4 -> 12 (c,s) pairs (compile-time indices after unroll)
#define UNPACK12(Ua, Ub, Uc, ca, sa) do {                                  \
    const u32 _u[12] = {Ua.x, Ua.y, Ua.z, Ua.w, Ub.x, Ub.y, Ub.z, Ub.w,    \
                        Uc.x, Uc.y, Uc.z, Uc.w};                           \
    _Pragma("unroll")                                                      \
    for (int a = 0; a < 12; ++a) {                                         \
        __half2 h2 = *reinterpret_cast<const __half2*>(&_u[a]);            \
        float2 f = __half22float2(h2);                                     \
        ca[a] = 1.0f - f.x;                                                \
        sa[a] = f.y;                                                       \
    }                                                                      \
} while (0)

// one phase = 3 layers (local strides 1,2,4) on packed w[8]
#define PHASE_ROTS(ca, sa, w)                                              \
    _Pragma("unroll")                                                      \
    for (int jj = 0; jj < 3; ++jj) {                                       \
        const int st = 1 << jj;                                            \
        _Pragma("unroll")                                                  \
        for (int m = 0; m < 8; ++m) {                                      \
            if (!(m & st)) {                                               \
                const int a = jj * 4 + inner_idx(m, jj);                   \
                rot2(w[m], w[m + st], ca[a], sa[a]);                       \
            }                                                              \
        }                                                                  \
    }

__global__ void __launch_bounds__(BLOCK, 6)
butterfly_kernel(const float* __restrict__ x, const uint4* __restrict__ TH4,
                 float* __restrict__ out) {
    __shared__ v2f buf[DIM];                // 32 KiB interleaved {r0[e], r1[e]}
    const int t = threadIdx.x;
    const long row0 = (long)blockIdx.x * 2;

    v2f w[8];
    float ca[12], sa[12];

    // ===== P1: e = 8t+k, layers 0-2; x direct from global =====
    {
        // x loads FIRST (HBM latency leads the queue), then angles (L2)
        const float* p0 = x + row0 * DIM + 8 * t;
        const float* p1 = p0 + DIM;
        float4 a = *(const float4*)(p0),     b = *(const float4*)(p0 + 4);
        float4 c = *(const float4*)(p1),     d = *(const float4*)(p1 + 4);
        uint4 A0 = TH4[0 * 512 + t], A1 = TH4[1 * 512 + t], A2 = TH4[2 * 512 + t];
        // prefetch P2 angles (fly across BAR)
        uint4 B0 = TH4[3 * 512 + t], B1 = TH4[4 * 512 + t], B2 = TH4[5 * 512 + t];

        w[0] = v2f{a.x, c.x}; w[1] = v2f{a.y, c.y};
        w[2] = v2f{a.z, c.z}; w[3] = v2f{a.w, c.w};
        w[4] = v2f{b.x, d.x}; w[5] = v2f{b.y, d.y};
        w[6] = v2f{b.z, d.z}; w[7] = v2f{b.w, d.w};
        UNPACK12(A0, A1, A2, ca, sa);
        PHASE_ROTS(ca, sa, w)
        // b128 writes: units (2Q', 2Q'+1), Q' = swzQ(4t+q)
        #pragma unroll
        for (int q = 0; q < 4; ++q) {
            *(float4*)(&buf[2 * swzQ(4 * t + q)]) =
                make_float4(w[2*q].x, w[2*q].y, w[2*q+1].x, w[2*q+1].y);
        }
        BAR();

        // ===== P2: e = 64(t>>3) + 8m + (t&7), layers 3-5 (b64) =====
        // prefetch P3 angles first (no wait), then consume B*
        uint4 C0 = TH4[6 * 512 + t], C1 = TH4[7 * 512 + t], C2 = TH4[8 * 512 + t];
        {
            const int eb = 64 * (t >> 3) + (t & 7);
            int ps[8];
            #pragma unroll
            for (int m = 0; m < 8; ++m) {
                ps[m] = uslot(eb + 8 * m);
                w[m] = buf[ps[m]];
            }
            UNPACK12(B0, B1, B2, ca, sa);
            PHASE_ROTS(ca, sa, w)
            #pragma unroll
            for (int m = 0; m < 8; ++m) buf[ps[m]] = w[m];   // own slots
        }
        BAR();

        // ===== P3: e = 512(t>>6) + 64m + (t&63), layers 6-8 (b64) =====
        // prefetch P4 angles first, then consume C*
        uint4 D0 = TH4[9 * 512 + t], D1 = TH4[10 * 512 + t], D2 = TH4[11 * 512 + t];
        {
            const int eb = 512 * (t >> 6) + (t & 63);
            int ps[8];
            #pragma unroll
            for (int m = 0; m < 8; ++m) {
                ps[m] = uslot(eb + 64 * m);
                w[m] = buf[ps[m]];
            }
            UNPACK12(C0, C1, C2, ca, sa);
            PHASE_ROTS(ca, sa, w)
            #pragma unroll
            for (int m = 0; m < 8; ++m) buf[ps[m]] = w[m];
        }
        BAR();

        // ===== P4: e = t + 512m, layers 9-11 (b64); store =====
        {
            #pragma unroll
            for (int m = 0; m < 8; ++m) w[m] = buf[uslot(t + 512 * m)];
            UNPACK12(D0, D1, D2, ca, sa);
            PHASE_ROTS(ca, sa, w)
            float* o0 = out + row0 * DIM + t;
            float* o1 = o0 + DIM;
            #pragma unroll
            for (int m = 0; m < 8; ++m) {
                o0[m << 9] = w[m].x;
                o1[m << 9] = w[m].y;
            }
        }
    }
}

extern "C" void kernel_launch(void* const* d_in, const int* in_sizes, int n_in,
                              void* d_out, int out_size, void* d_ws, size_t ws_size,
                              hipStream_t stream) {
    (void)in_sizes; (void)n_in; (void)out_size; (void)ws_size;
    const float* x      = (const float*)d_in[0];
    const float* angles = (const float*)d_in[1];
    float* out = (float*)d_out;

    const int n = LAYERS * NANG;                    // 24576 angles, 96 KiB table
    cs_kernel<<<(n + 255) / 256, 256, 0, stream>>>(angles, (u32*)d_ws, n);
    butterfly_kernel<<<BATCH / 2, BLOCK, 0, stream>>>(x, (const uint4*)d_ws, out);
}